// Round 13
// baseline (183.600 us; speedup 1.0000x reference)
//
#include <hip/hip_runtime.h>

typedef unsigned short u16;
typedef __attribute__((ext_vector_type(8))) short bf16x8;
typedef __attribute__((ext_vector_type(4))) float f32x4;

#define Bb 2
#define Tt 2048
#define Dd 1024
#define Hh 16
#define HD 64
#define NTOK (Bb*Tt)   // 4096
#define QKVN (3*Dd)    // 3072

__device__ __forceinline__ u16 f2b(float f) {
    unsigned u = __float_as_uint(f);
    unsigned r = (u + 0x7fffu + ((u >> 16) & 1u)) >> 16;
    return (u16)r;
}

// async global->LDS, 16B per lane; LDS dest = wave-uniform base + lane*16
__device__ __forceinline__ void g2l16(const u16* g, u16* l) {
    __builtin_amdgcn_global_load_lds(
        (const __attribute__((address_space(1))) unsigned int*)g,
        (__attribute__((address_space(3))) unsigned int*)l,
        16, 0, 0);
}

// pack two fp32 -> two bf16 (truncate) in one v_perm
__device__ __forceinline__ unsigned pk2(float lo, float hi) {
    return __builtin_amdgcn_perm(__float_as_uint(hi), __float_as_uint(lo), 0x07060302u);
}

// ---------------- fused fp32 -> bf16 convert ----------------
#define N4X  (NTOK * Dd / 4)
#define N4WQ (3 * Dd * Dd / 4)
#define N4WP (Dd * Dd / 4)
__global__ void cvt_all(const float* __restrict__ x, const float* __restrict__ wq,
                        const float* __restrict__ wp, u16* __restrict__ xb,
                        u16* __restrict__ wqb, u16* __restrict__ wpb) {
    int i = blockIdx.x * blockDim.x + threadIdx.x;
    const float* src; u16* dst; int j;
    if (i < N4X)                { src = x;  dst = xb;  j = i; }
    else if (i < N4X + N4WQ)    { src = wq; dst = wqb; j = i - N4X; }
    else                        { src = wp; dst = wpb; j = i - N4X - N4WQ; }
    float4 f = ((const float4*)src)[j];
    ushort4 o;
    o.x = f2b(f.x); o.y = f2b(f.y); o.z = f2b(f.z); o.w = f2b(f.w);
    ((ushort4*)dst)[j] = o;
}

// ---------------- GEMM1: qkv = x @ Wqkv^T + b. 128x128 tile, BK=64 ----
#define TRS 136   // transpose LDS stride (u16)

__global__ __launch_bounds__(256, 3)
void gemm_qkv(const u16* __restrict__ A, const u16* __restrict__ Bt,
              const float* __restrict__ bias,
              u16* __restrict__ C16, u16* __restrict__ Vt) {
    const int N = QKVN, K = Dd;
    __shared__ alignas(16) u16 smem[128 * TRS];
    u16* As = smem;
    u16* Bs = smem + 8192;
    const int tid = threadIdx.x;
    const int wave = tid >> 6, lane = tid & 63;
    const int quad = lane >> 4, l16 = lane & 15;
    const int wm = (wave & 1) * 64, wn = (wave >> 1) * 64;
    const int m0 = blockIdx.x * 128, n0 = blockIdx.y * 128;
    const int lrow = lane >> 2, lcol = (lane & 3) << 3;

    f32x4 acc[4][4];
#pragma unroll
    for (int i = 0; i < 4; ++i)
#pragma unroll
        for (int j = 0; j < 4; ++j)
            acc[i][j] = (f32x4){0.f, 0.f, 0.f, 0.f};

    for (int k0 = 0; k0 < K; k0 += 64) {
#pragma unroll
        for (int h = 0; h < 2; ++h)
#pragma unroll
            for (int c = 0; c < 2; ++c) {
                const int rb = (c * 4 + wave) * 16;
                g2l16(A  + (size_t)(m0 + rb + lrow) * K + k0 + h * 32 + lcol,
                      &As[h * 4096 + rb * 32 + (lane << 3)]);
                g2l16(Bt + (size_t)(n0 + rb + lrow) * K + k0 + h * 32 + lcol,
                      &Bs[h * 4096 + rb * 32 + (lane << 3)]);
            }
        __syncthreads();
        bf16x8 a[4][2], b[4][2];
#pragma unroll
        for (int h = 0; h < 2; ++h) {
#pragma unroll
            for (int i = 0; i < 4; ++i)
                a[i][h] = *(const bf16x8*)(&As[h * 4096 + (wm + i * 16 + l16) * 32 + quad * 8]);
#pragma unroll
            for (int i = 0; i < 4; ++i)
                b[i][h] = *(const bf16x8*)(&Bs[h * 4096 + (wn + i * 16 + l16) * 32 + quad * 8]);
        }
#pragma unroll
        for (int h = 0; h < 2; ++h)
#pragma unroll
            for (int i = 0; i < 4; ++i)
#pragma unroll
                for (int j = 0; j < 4; ++j)
                    acc[i][j] = __builtin_amdgcn_mfma_f32_16x16x32_bf16(a[i][h], b[j][h], acc[i][j], 0, 0, 0);
        __syncthreads();
    }

    float b4[4];
#pragma unroll
    for (int j = 0; j < 4; ++j) b4[j] = bias[n0 + wn + j * 16 + l16];
    const bool isV = (n0 >= 2 * Dd);   // block-uniform

    if (!isV) {
#pragma unroll
        for (int i = 0; i < 4; ++i)
#pragma unroll
            for (int j = 0; j < 4; ++j)
#pragma unroll
                for (int r = 0; r < 4; ++r) {
                    int m = m0 + wm + i * 16 + quad * 4 + r;
                    int n = n0 + wn + j * 16 + l16;
                    C16[(size_t)m * N + n] = f2b(acc[i][j][r] + b4[j]);
                }
    } else {
#pragma unroll
        for (int i = 0; i < 4; ++i)
#pragma unroll
            for (int j = 0; j < 4; ++j)
#pragma unroll
                for (int r = 0; r < 4; ++r) {
                    int ml = wm + i * 16 + quad * 4 + r;
                    int nl = wn + j * 16 + l16;
                    smem[nl * TRS + ml] = f2b(acc[i][j][r] + b4[j]);
                }
        __syncthreads();
        const int bidx = m0 >> 11, t0 = m0 & 2047;
        const int nl = tid >> 1, toff = (tid & 1) * 64;
        u16* dst = Vt + (size_t)bidx * (Hh * HD * Tt)
                      + (size_t)(n0 - 2 * Dd + nl) * Tt + t0 + toff;
        const u16* srcl = &smem[nl * TRS + toff];
#pragma unroll
        for (int k = 0; k < 8; ++k)
            *(uint4*)(dst + k * 8) = *(const uint4*)(srcl + k * 8);
    }
}

// ---------------- GEMM2: out = attn @ Wproj^T + b. 128x64 tiles, BK=64, fp32 out ----------------
__global__ __launch_bounds__(256, 2)
void gemm_proj(const u16* __restrict__ A, const u16* __restrict__ Bt,
               const float* __restrict__ bias, float* __restrict__ Co) {
    const int N = Dd, K = Dd;
    __shared__ alignas(16) u16 As[2 * 128 * 32];
    __shared__ alignas(16) u16 Bs[2 * 64 * 32];
    const int tid = threadIdx.x;
    const int wave = tid >> 6, lane = tid & 63;
    const int quad = lane >> 4, l16 = lane & 15;
    const int wm = (wave & 1) * 64, wn = (wave >> 1) * 32;
    const int m0 = blockIdx.x * 128, n0 = blockIdx.y * 64;
    const int lrow = lane >> 2, lcol = (lane & 3) << 3;

    f32x4 acc[4][2];
#pragma unroll
    for (int i = 0; i < 4; ++i)
#pragma unroll
        for (int j = 0; j < 2; ++j)
            acc[i][j] = (f32x4){0.f, 0.f, 0.f, 0.f};

    for (int k0 = 0; k0 < K; k0 += 64) {
#pragma unroll
        for (int h = 0; h < 2; ++h) {
#pragma unroll
            for (int c = 0; c < 2; ++c) {
                const int rb = (c * 4 + wave) * 16;
                g2l16(A + (size_t)(m0 + rb + lrow) * K + k0 + h * 32 + lcol,
                      &As[h * 4096 + rb * 32 + (lane << 3)]);
            }
            g2l16(Bt + (size_t)(n0 + wave * 16 + lrow) * K + k0 + h * 32 + lcol,
                  &Bs[h * 2048 + (wave * 16) * 32 + (lane << 3)]);
        }
        __syncthreads();
        bf16x8 a[4][2], b[2][2];
#pragma unroll
        for (int h = 0; h < 2; ++h) {
#pragma unroll
            for (int i = 0; i < 4; ++i)
                a[i][h] = *(const bf16x8*)(&As[h * 4096 + (wm + i * 16 + l16) * 32 + quad * 8]);
#pragma unroll
            for (int j = 0; j < 2; ++j)
                b[j][h] = *(const bf16x8*)(&Bs[h * 2048 + (wn + j * 16 + l16) * 32 + quad * 8]);
        }
#pragma unroll
        for (int h = 0; h < 2; ++h)
#pragma unroll
            for (int i = 0; i < 4; ++i)
#pragma unroll
                for (int j = 0; j < 2; ++j)
                    acc[i][j] = __builtin_amdgcn_mfma_f32_16x16x32_bf16(a[i][h], b[j][h], acc[i][j], 0, 0, 0);
        __syncthreads();
    }

    float b2[2];
#pragma unroll
    for (int j = 0; j < 2; ++j) b2[j] = bias[n0 + wn + j * 16 + l16];

#pragma unroll
    for (int i = 0; i < 4; ++i)
#pragma unroll
        for (int j = 0; j < 2; ++j)
#pragma unroll
            for (int r = 0; r < 4; ++r) {
                int m = m0 + wm + i * 16 + quad * 4 + r;
                int n = n0 + wn + j * 16 + l16;
                Co[(size_t)m * N + n] = acc[i][j][r] + b2[j];
            }
}

// ---------------- flash attention: 8-wave paired blocks, shared K/V stream ----------------
// 512 threads: waves 0-3 own heavy tile (qtH=31-p) q-rows, waves 4-7 own light (qtL=p).
// ONE K/V staging stream serves both tiles (light's key range is a prefix of heavy's).
// Each wave keeps the single-tile register footprint. Phases are wave-uniform.
// Grid 512 blocks x 8 waves = 4096 waves = exactly 4 waves/SIMD (full residency).
#define LKP 80
#define PSP 84
#define FMX 24.0f
#define MFMA16(a,b,c) __builtin_amdgcn_mfma_f32_16x16x32_bf16(a, b, c, 0, 0, 0)

template<bool MASK>
__device__ __forceinline__ void tile_iter(
    const u16* Kcur, const u16* Vcur, u16* Pw,
    const bf16x8 (&aq)[2], f32x4 (&o)[4], float& lsum,
    const float (&mb)[16], int l16, int quad, float sc)
{
    f32x4 s[4];
#pragma unroll
    for (int nt = 0; nt < 4; ++nt) {
        f32x4 z = (f32x4){0.f, 0.f, 0.f, 0.f};
#pragma unroll
        for (int kk = 0; kk < 2; ++kk) {
            bf16x8 ak = *(const bf16x8*)(&Kcur[(nt * 16 + l16) * LKP + kk * 32 + quad * 8]);
            z = MFMA16(ak, aq[kk], z);
        }
        s[nt] = z;
    }
#pragma unroll
    for (int nt = 0; nt < 4; ++nt)
#pragma unroll
        for (int r = 0; r < 4; ++r) {
            float p = exp2f(__builtin_fmaf(s[nt][r], sc, MASK ? mb[nt * 4 + r] : -FMX));
            s[nt][r] = p;
            lsum += p;
        }
#pragma unroll
    for (int nt = 0; nt < 4; ++nt) {
        uint2 d;
        d.x = pk2(s[nt][0], s[nt][1]);
        d.y = pk2(s[nt][2], s[nt][3]);
        *(uint2*)(&Pw[l16 * PSP + nt * 16 + quad * 4]) = d;
    }
#pragma unroll
    for (int kk = 0; kk < 2; ++kk) {
        bf16x8 bp = *(const bf16x8*)(&Pw[l16 * PSP + kk * 32 + quad * 8]);
#pragma unroll
        for (int nt = 0; nt < 4; ++nt) {
            bf16x8 av = *(const bf16x8*)(&Vcur[(nt * 16 + l16) * LKP + kk * 32 + quad * 8]);
            o[nt] = MFMA16(av, bp, o[nt]);
        }
    }
}

__global__ __launch_bounds__(512, 4)
void attn_fwd(const u16* __restrict__ qkv, const u16* __restrict__ Vt,
              u16* __restrict__ Ao) {
    // complementary-p remap: co-resident blocks (x,y) and (x,y+16) get p and 15-p
    // -> per-CU staging totals uniform: (32-p)+(17+p) = 49 tiles.
    const int p = ((int)blockIdx.y < 16) ? (int)blockIdx.x : 15 - (int)blockIdx.x;
    const int qtH = 31 - p, qtL = p;
    const int bh = blockIdx.y;
    const int hh = bh & (Hh - 1), bidx = bh >> 4;
    const u16* Qp = qkv + (size_t)bidx * Tt * QKVN + hh * HD;
    const u16* Kp = Qp + Dd;
    const u16* Vp = Vt + (size_t)bh * HD * Tt;
    const int tid = threadIdx.x;
    const int wave = tid >> 6, lane = tid & 63;
    const int quad = lane >> 4, l16 = lane & 15;
    const int w4 = wave & 3;              // row-group within my tile
    const bool isH = wave < 4;
    const int myqt = isH ? qtH : qtL;

    __shared__ alignas(16) u16 Ks[2][64 * LKP];
    __shared__ alignas(16) u16 Vs[2][64 * LKP];
    __shared__ alignas(16) u16 Ps[8][16 * PSP];
    u16* Pw = &Ps[wave][0];

    // staging: 512 threads, one uint4 of K and one of V each (64 rows x 8 chunks)
    const int srow = tid >> 3, scol = (tid & 7) << 3;
    const int st = srow * LKP + scol;
    const float sc = 0.125f * 1.44269504f;

    // per-thread diagonal mask bias (tile-local causal predicate)
    float mb[16];
#pragma unroll
    for (int nt = 0; nt < 4; ++nt)
#pragma unroll
        for (int r = 0; r < 4; ++r)
            mb[nt * 4 + r] = (nt * 16 + quad * 4 + r <= w4 * 16 + l16) ? -FMX : -250.0f;

    const int qrow_g = myqt * 64 + w4 * 16 + l16;
    bf16x8 aq[2];
#pragma unroll
    for (int kk = 0; kk < 2; ++kk)
        aq[kk] = *(const bf16x8*)(Qp + (size_t)qrow_g * QKVN + kk * 32 + quad * 8);

    f32x4 o[4];
#pragma unroll
    for (int nt = 0; nt < 4; ++nt) o[nt] = (f32x4){0.f, 0.f, 0.f, 0.f};
    float lsum = 0.f;

    // preload tile 0 into buffer 0
    {
        uint4 kr = *(const uint4*)(Kp + (size_t)srow * QKVN + scol);
        uint4 vr = *(const uint4*)(Vp + (size_t)srow * Tt + scol);
        *(uint4*)(&Ks[0][st]) = kr;
        *(uint4*)(&Vs[0][st]) = vr;
    }
    __syncthreads();

    const u16* kp = Kp + (size_t)(64 + srow) * QKVN + scol;
    const u16* vp = Vp + (size_t)srow * Tt + 64 + scol;
    u16* Kcur = &Ks[0][0]; u16* Knxt = &Ks[1][0];
    u16* Vcur = &Vs[0][0]; u16* Vnxt = &Vs[1][0];

#define PREFETCH \
    uint4 kr = *(const uint4*)kp; uint4 vr = *(const uint4*)vp; \
    kp += (size_t)64 * QKVN; vp += 64;

#define STAGE_SWAP \
    *(uint4*)(&Knxt[st]) = kr; *(uint4*)(&Vnxt[st]) = vr; \
    { u16* t = Kcur; Kcur = Knxt; Knxt = t; t = Vcur; Vcur = Vnxt; Vnxt = t; } \
    __syncthreads();

    // phase A: kt < qtL — all 8 waves compute, no masks
    for (int kt = 0; kt < qtL; ++kt) {
        PREFETCH
        tile_iter<false>(Kcur, Vcur, Pw, aq, o, lsum, mb, l16, quad, sc);
        STAGE_SWAP
    }
    // phase B: kt == qtL — light waves hit their diagonal (qtL < qtH so prefetch valid)
    {
        PREFETCH
        if (isH) tile_iter<false>(Kcur, Vcur, Pw, aq, o, lsum, mb, l16, quad, sc);
        else     tile_iter<true>(Kcur, Vcur, Pw, aq, o, lsum, mb, l16, quad, sc);
        STAGE_SWAP
    }
    // phase C: qtL < kt < qtH — heavy waves compute; light waves stage+barrier only
    for (int kt = qtL + 1; kt < qtH; ++kt) {
        PREFETCH
        if (isH) tile_iter<false>(Kcur, Vcur, Pw, aq, o, lsum, mb, l16, quad, sc);
        STAGE_SWAP
    }
    // phase D: kt == qtH — heavy diagonal, no prefetch
    if (isH) tile_iter<true>(Kcur, Vcur, Pw, aq, o, lsum, mb, l16, quad, sc);

    // epilogue (per wave): reduce l across quads, normalize, packed b64 stores
    lsum += __shfl_xor(lsum, 16, 64);
    lsum += __shfl_xor(lsum, 32, 64);
    const float rinv = 1.0f / lsum;
    u16* orow = Ao + ((size_t)bidx * Tt + qrow_g) * Dd + hh * HD;
#pragma unroll
    for (int nt = 0; nt < 4; ++nt) {
        ushort4 p4;
        p4.x = f2b(o[nt][0] * rinv); p4.y = f2b(o[nt][1] * rinv);
        p4.z = f2b(o[nt][2] * rinv); p4.w = f2b(o[nt][3] * rinv);
        *(ushort4*)(orow + nt * 16 + quad * 4) = p4;
    }
}

extern "C" void kernel_launch(void* const* d_in, const int* in_sizes, int n_in,
                              void* d_out, int out_size, void* d_ws, size_t ws_size,
                              hipStream_t stream) {
    const float* x      = (const float*)d_in[0];
    const float* W_qkv  = (const float*)d_in[1];
    const float* b_qkv  = (const float*)d_in[2];
    const float* W_proj = (const float*)d_in[3];
    const float* b_proj = (const float*)d_in[4];
    float* out = (float*)d_out;

    // 48 MiB layout:
    //   [0,2)    Wprojb   (live until gemm2)
    //   [2,8)    Wqkvb    (dead after gemm1)  \__ attnb aliases [2,10)
    //   [8,16)   xb       (dead after gemm1)  /
    //   [16,40)  qkvb     (dead after attn)
    //   [40,48)  Vtb      (dead after attn)
    char* ws = (char*)d_ws;
    u16* Wprojb = (u16*)(ws);
    u16* Wqkvb  = (u16*)(ws + (2u << 20));
    u16* xb     = (u16*)(ws + (8u << 20));
    u16* qkvb   = (u16*)(ws + (16u << 20));
    u16* Vtb    = (u16*)(ws + (40u << 20));
    u16* attnb  = (u16*)(ws + (2u << 20));   // aliases Wqkvb+xb (dead by then)

    cvt_all<<<(N4X + N4WQ + N4WP) / 256, 256, 0, stream>>>(x, W_qkv, W_proj, xb, Wqkvb, Wprojb);

    {
        dim3 grid(NTOK / 128, QKVN / 128);   // 32 x 24 = 768 blocks
        gemm_qkv<<<grid, 256, 0, stream>>>(xb, Wqkvb, b_qkv, qkvb, Vtb);
    }
    {
        dim3 grid(16, Bb * Hh);   // 16 pairs x 32 bh = 512 blocks x 8 waves
        attn_fwd<<<grid, 512, 0, stream>>>(qkvb, Vtb, attnb);
    }
    {
        dim3 grid(NTOK / 128, Dd / 64);   // 32 x 16 = 512 blocks
        gemm_proj<<<grid, 256, 0, stream>>>(attnb, Wprojb, b_proj, out);
    }
}